// Round 5
// baseline (52.672 us; speedup 1.0000x reference)
//
#include <hip/hip_runtime.h>
#include <math.h>

// ---------------------------------------------------------------------------
// YOLO loss, forward only — SINGLE fused dispatch.
//   block 0   : assign prologue — 512 targets, LDS hash dedup (CAS claim +
//               atomicMax scan-order + atomicOr target mask) -> global
//               list+count, reset done, fence, publish ready-flag (magic).
//   all blocks: dense obj loss (t=0 baseline) on their slice — independent
//               of assignment, hides block 0's assign latency; block partial
//               to dpart. Then spin on ready-flag (1 thread, s_sleep).
//   waves     : 4 waves/block x 384 blocks = 1536 = MAXPOS positive cells;
//               obj correction (t=0 -> t=1), class loss spread over 80
//               lanes, box GIoU+L1 on lane 0 -> ppart.
//   last block: (done-counter protocol) reduce dpart+ppart, write loss,
//               reset ready-flag to 0 (no state left across calls).
// ---------------------------------------------------------------------------

#define IMGF 640.0f
#define NCLS 80
#define NAK 3
#define NB 16
#define NT 32
#define H0 80
#define H1 40
#define H2 20
#define NCELL0 (NB * NAK * H0 * H0) /* 307200 */
#define NCELL1 (NB * NAK * H1 * H1) /*  76800 */
#define NCELL2 (NB * NAK * H2 * H2) /*  19200 */
#define NCELL_TOTAL (NCELL0 + NCELL1 + NCELL2) /* 403200 */
#define MAXPOS 1536 /* <=3 unique cells per target x 512 targets */
#define NDENSE (NCELL_TOTAL / 4) /* 100800 float4 groups */
#define NBLOCKS 384
#define HSIZE 4096
#define READY_MAGIC 0x5A17C0DEu

__device__ __constant__ float c_anchors[9][2] = {
    {0.0156f, 0.0203f}, {0.025f, 0.0469f}, {0.0516f, 0.0359f},
    {0.0469f, 0.0953f}, {0.0969f, 0.0703f}, {0.0922f, 0.1859f},
    {0.1813f, 0.1406f}, {0.2438f, 0.3094f}, {0.5828f, 0.5094f}};

__device__ inline float sgm(float x) { return 1.f / (1.f + expf(-x)); }
__device__ inline float bcef(float x, float t) {
    return fmaxf(x, 0.f) - x * t + log1pf(expf(-fabsf(x)));
}
__device__ inline float focal_bce(float x, float t) {
    float p = sgm(x);
    float pt = p * t + (1.f - p) * (1.f - t);
    float at = 0.25f * t + 0.75f * (1.f - t);
    float omp = 1.f - pt;
    return at * omp * omp * bcef(x, t);
}

template <int HWC>
__device__ inline float obj4(const float* __restrict__ p, int cis, float inv) {
    int q = cis / HWC; // (b*3+a); compile-time divisor -> magic mul
    int off = cis - q * HWC;
    const float4 v =
        *reinterpret_cast<const float4*>(p + ((size_t)q * 85 + 4) * HWC + off);
    return (focal_bce(v.x, 0.f) + focal_bce(v.y, 0.f) + focal_bce(v.z, 0.f) +
            focal_bce(v.w, 0.f)) *
           inv;
}

__global__ __launch_bounds__(256, 2) void yolo_fused(
    const float* __restrict__ p0, const float* __restrict__ p1,
    const float* __restrict__ p2, const float* __restrict__ boxes,
    const int* __restrict__ labels, int4* __restrict__ list,
    int* __restrict__ countg, unsigned* __restrict__ flag,
    int* __restrict__ done, float* __restrict__ dpart,
    float* __restrict__ ppart, float* __restrict__ out) {
    __shared__ int hkey[HSIZE];
    __shared__ int hord[HSIZE];
    __shared__ unsigned htm[HSIZE];
    __shared__ int lcount;
    __shared__ float redd[4];
    __shared__ float redf[4][3];
    __shared__ int amLast;

    // ---------------- block 0: assign prologue ----------------
    if (blockIdx.x == 0) {
        for (int i = threadIdx.x; i < HSIZE; i += 256) {
            hkey[i] = -1;
            hord[i] = -1;
            htm[i] = 0u;
        }
        if (threadIdx.x == 0) lcount = 0;
        __syncthreads();
        for (int half = 0; half < 2; half++) {
            int t = threadIdx.x + (half << 8);
            int b = t >> 5;
            int n = t & 31;
            int lab = labels[t];
            if (lab >= 0 && lab < NCLS) {
                float x1 = boxes[4 * t + 0], y1 = boxes[4 * t + 1];
                float x2 = boxes[4 * t + 2], y2 = boxes[4 * t + 3];
                float bw = fminf(fmaxf((x2 - x1) / IMGF, 1e-6f), 1.0f);
                float bh = fminf(fmaxf((y2 - y1) / IMGF, 1e-6f), 1.0f);
                float area = bw * bh;
                float best = -1.0f;
                int bestk = 0;
#pragma unroll
                for (int k = 0; k < 9; k++) { // strict > == argmax first-max
                    float aw = c_anchors[k][0], ah = c_anchors[k][1];
                    float inter = fminf(bw, aw) * fminf(bh, ah);
                    float iou = inter / (area + aw * ah - inter + 1e-9f);
                    if (iou > best) { best = iou; bestk = k; }
                }
                int s = bestk / 3, a = bestk - 3 * s;
                float cx =
                    fminf(fmaxf((x1 + x2) * 0.5f / IMGF, 0.f), 1.f - 1e-6f);
                float cy =
                    fminf(fmaxf((y1 + y2) * 0.5f / IMGF, 0.f), 1.f - 1e-6f);
                int hw = (s == 0) ? H0 : ((s == 1) ? H1 : H2);
                int basecell =
                    (s == 0) ? 0 : ((s == 1) ? NCELL0 : (NCELL0 + NCELL1));
                float gx = cx * (float)hw, gy = cy * (float)hw;
                int gi = min(max((int)floorf(gx), 0), hw - 1);
                int gj = min(max((int)floorf(gy), 0), hw - 1);
                float fx = gx - (float)gi, fy = gy - (float)gj;
                const int dis[5] = {0, -1, 1, 0, 0};
                const int djs[5] = {0, 0, 0, -1, 1};
                bool keep[5];
                keep[0] = true;
                keep[1] = (fx < 0.5f);
                keep[2] = (fx >= 0.5f);
                keep[3] = (fy < 0.5f);
                keep[4] = (fy >= 0.5f);
#pragma unroll
                for (int c = 0; c < 5; c++) {
                    if (!keep[c]) continue;
                    int ngi = gi + dis[c], ngj = gj + djs[c];
                    if (ngi < 0 || ngi >= hw || ngj < 0 || ngj >= hw) continue;
                    int cell = basecell + ((b * NAK + a) * hw + ngj) * hw + ngi;
                    unsigned h = ((unsigned)cell * 2654435761u) >> 20;
                    while (true) {
                        int old = atomicCAS(&hkey[h], -1, cell);
                        if (old == -1 || old == cell) break;
                        h = (h + 1) & (HSIZE - 1);
                    }
                    // scan-order key: last-writer-wins (XLA scatter-set)
                    atomicMax(&hord[h], c * (NB * NT) + t);
                    atomicOr(&htm[h], 1u << n);
                }
            }
        }
        __syncthreads();
        for (int i = threadIdx.x; i < HSIZE; i += 256) {
            if (hkey[i] >= 0) {
                int p = atomicAdd(&lcount, 1);
                list[p] = make_int4(hkey[i], hord[i], (int)htm[i], 0);
            }
        }
        __syncthreads();
        if (threadIdx.x == 0) {
            *countg = lcount;
            *done = 0;
            __threadfence();
            __hip_atomic_store(flag, READY_MAGIC, __ATOMIC_RELAXED,
                               __HIP_MEMORY_SCOPE_AGENT);
        }
    }

    // ---------------- dense obj: all blocks, t = 0 baseline ----------------
    float obj = 0.f;
    for (int i = blockIdx.x * 256 + threadIdx.x; i < NDENSE;
         i += NBLOCKS * 256) {
        int c4 = i * 4;
        if (c4 < NCELL0)
            obj += obj4<H0 * H0>(p0, c4, 1.f / (float)NCELL0);
        else if (c4 < NCELL0 + NCELL1)
            obj += obj4<H1 * H1>(p1, c4 - NCELL0, 1.f / (float)NCELL1);
        else
            obj +=
                obj4<H2 * H2>(p2, c4 - NCELL0 - NCELL1, 1.f / (float)NCELL2);
    }
#pragma unroll
    for (int off = 32; off > 0; off >>= 1) obj += __shfl_down(obj, off, 64);
    if ((threadIdx.x & 63) == 0) redd[threadIdx.x >> 6] = obj;
    __syncthreads();
    if (threadIdx.x == 0)
        dpart[blockIdx.x] = redd[0] + redd[1] + redd[2] + redd[3];

    // ---------------- wait for assignment ----------------
    if (threadIdx.x == 0) {
        while (__hip_atomic_load(flag, __ATOMIC_RELAXED,
                                 __HIP_MEMORY_SCOPE_AGENT) != READY_MAGIC)
            __builtin_amdgcn_s_sleep(1);
    }
    __syncthreads();
    __threadfence(); // acquire: list/countg now visible
    int cnt = *countg;

    // ---------------- positives: 4 waves/block ----------------
    int w = blockIdx.x * 4 + (threadIdx.x >> 6);
    int lane = threadIdx.x & 63;
    if (w < cnt) {
        int4 rec = list[w];
        int idx = rec.x;
        unsigned tm = (unsigned)rec.z;
        const float* p;
        int hw, s, base;
        float inv;
        if (idx < NCELL0) {
            p = p0; hw = H0; s = 0; base = 0; inv = 1.f / (float)NCELL0;
        } else if (idx < NCELL0 + NCELL1) {
            p = p1; hw = H1; s = 1; base = NCELL0; inv = 1.f / (float)NCELL1;
        } else {
            p = p2; hw = H2; s = 2; base = NCELL0 + NCELL1;
            inv = 1.f / (float)NCELL2;
        }
        int cell = idx - base;
        int x = cell % hw;
        int r = cell / hw;
        int y = r % hw;
        r /= hw;
        int a = r % NAK;
        int b = r / NAK;
        size_t HW = (size_t)hw * hw;
        const float* pc =
            p + (size_t)(b * 255 + a * 85) * HW + (size_t)y * hw + x;
        // class loss: 80 classes spread over lanes (2 parallel rounds)
        float cl = 0.f;
#pragma unroll
        for (int rep = 0; rep < 2; rep++) {
            int c = lane + 64 * rep;
            if (c < NCLS) {
                float tt = 0.f;
                unsigned tmp = tm;
                while (tmp) {
                    int n = __ffs(tmp) - 1;
                    tmp &= tmp - 1;
                    if (labels[(b << 5) + n] == c) tt = 1.f;
                }
                cl += bcef(pc[(size_t)(5 + c) * HW], tt);
            }
        }
#pragma unroll
        for (int off = 32; off > 0; off >>= 1) cl += __shfl_down(cl, off, 64);
        if (lane == 0) {
            // obj correction t=0 -> t=1 (dense pass assumed t=0)
            float pobj = pc[4 * HW];
            float objc = (focal_bce(pobj, 1.f) - focal_bce(pobj, 0.f)) * inv;
            // box loss: decode last scatter writer
            int wn = rec.y & (NB * NT - 1); // order % 512
            float bx1 = boxes[4 * wn + 0], by1 = boxes[4 * wn + 1];
            float bx2 = boxes[4 * wn + 2], by2 = boxes[4 * wn + 3];
            float tw = fminf(fmaxf((bx2 - bx1) / IMGF, 1e-6f), 1.f);
            float th = fminf(fmaxf((by2 - by1) / IMGF, 1e-6f), 1.f);
            float tcx =
                fminf(fmaxf((bx1 + bx2) * 0.5f / IMGF, 0.f), 1.f - 1e-6f);
            float tcy =
                fminf(fmaxf((by1 + by2) * 0.5f / IMGF, 0.f), 1.f - 1e-6f);
            float l0 = pc[0], l1 = pc[HW], l2 = pc[2 * HW], l3 = pc[3 * HW];
            float pcx = ((float)x + 2.f * sgm(l0) - 0.5f) / (float)hw;
            float pcy = ((float)y + 2.f * sgm(l1) - 0.5f) / (float)hw;
            float sw = 2.f * sgm(l2), sh = 2.f * sgm(l3);
            float pw = sw * sw * c_anchors[s * 3 + a][0];
            float ph = sh * sh * c_anchors[s * 3 + a][1];
            float px1 = pcx - pw * 0.5f, px2 = pcx + pw * 0.5f;
            float py1 = pcy - ph * 0.5f, py2 = pcy + ph * 0.5f;
            float tx1 = tcx - tw * 0.5f, tx2 = tcx + tw * 0.5f;
            float ty1 = tcy - th * 0.5f, ty2 = tcy + th * 0.5f;
            float iw = fmaxf(fminf(px2, tx2) - fmaxf(px1, tx1), 0.f);
            float ih = fmaxf(fminf(py2, ty2) - fmaxf(py1, ty1), 0.f);
            float it = iw * ih;
            float un = pw * ph + tw * th - it + 1e-9f;
            float iou = it / un;
            float enc = (fmaxf(px2, tx2) - fminf(px1, tx1)) *
                            (fmaxf(py2, ty2) - fminf(py1, ty1)) +
                        1e-9f;
            float giou = iou - (enc - un) / enc;
            float l1l = fabsf(pcx - tcx) + fabsf(pcy - tcy) + fabsf(pw - tw) +
                        fabsf(ph - th);
            ppart[3 * w] = cl;
            ppart[3 * w + 1] = 1.f - giou + l1l;
            ppart[3 * w + 2] = objc;
        }
    }

    // ---------------- fused finalize: last-done block ----------------
    __syncthreads();
    if (threadIdx.x == 0) {
        __threadfence(); // release our dpart/ppart writes
        amLast = (atomicAdd(done, 1) == NBLOCKS - 1) ? 1 : 0;
    }
    __syncthreads();
    if (amLast) {
        __threadfence(); // acquire other blocks' writes
        float o = 0.f, cls = 0.f, box = 0.f;
        for (int i = threadIdx.x; i < NBLOCKS; i += 256) o += dpart[i];
        for (int i = threadIdx.x; i < cnt; i += 256) {
            cls += ppart[3 * i];
            box += ppart[3 * i + 1];
            o += ppart[3 * i + 2];
        }
#pragma unroll
        for (int off = 32; off > 0; off >>= 1) {
            o += __shfl_down(o, off, 64);
            cls += __shfl_down(cls, off, 64);
            box += __shfl_down(box, off, 64);
        }
        int wv = threadIdx.x >> 6;
        if ((threadIdx.x & 63) == 0) {
            redf[wv][0] = o;
            redf[wv][1] = cls;
            redf[wv][2] = box;
        }
        __syncthreads();
        if (threadIdx.x == 0) {
            float oo = redf[0][0] + redf[1][0] + redf[2][0] + redf[3][0];
            float cc = redf[0][1] + redf[1][1] + redf[2][1] + redf[3][1];
            float bb = redf[0][2] + redf[1][2] + redf[2][2] + redf[3][2];
            float d = fmaxf((float)cnt, 1.f);
            out[0] = oo + (cc + 5.f * bb) / d;
            *flag = 0u; // disarm for next call (no cross-call state)
        }
    }
}

extern "C" void kernel_launch(void* const* d_in, const int* in_sizes, int n_in,
                              void* d_out, int out_size, void* d_ws,
                              size_t ws_size, hipStream_t stream) {
    const float* p0 = (const float*)d_in[0];
    const float* p1 = (const float*)d_in[1];
    const float* p2 = (const float*)d_in[2];
    const float* boxes = (const float*)d_in[3];
    const int* labels = (const int*)d_in[4];
    float* out = (float*)d_out;

    // ws layout (everything read this call is written this call; flag is
    // self-disarming: reset to 0 by the last block each call):
    // [list int4 x MAXPOS][countg][flag][done][pad][dpart f32 x NBLOCKS]
    // [ppart f32 x MAXPOS*3]
    char* ws = (char*)d_ws;
    int4* list = (int4*)ws;
    size_t off = (size_t)MAXPOS * 16; // 24576
    int* countg = (int*)(ws + off);
    unsigned* flag = (unsigned*)(ws + off + 4);
    int* done = (int*)(ws + off + 8);
    off += 16;
    float* dpart = (float*)(ws + off);
    off += (size_t)NBLOCKS * 4;
    float* ppart = (float*)(ws + off);

    yolo_fused<<<NBLOCKS, 256, 0, stream>>>(p0, p1, p2, boxes, labels, list,
                                            countg, flag, done, dpart, ppart,
                                            out);
}

// Round 6
// 30.359 us; speedup vs baseline: 1.7350x; 1.7350x over previous
//
#include <hip/hip_runtime.h>
#include <math.h>

// ---------------------------------------------------------------------------
// YOLO loss, forward only — 2 dispatches, 0 memsets, 0 spin protocols.
//   k1 : blocks 0..383 stream the obj channel (focal-BCE with t=0 baseline,
//        coalesced float4) -> dpart[block]. Block 384 alone runs the target
//        assignment (LDS hash dedup: CAS claim + atomicMax scan-order +
//        atomicOr target-mask), compacts to list+count, resets done.
//        Kernel boundary = synchronization (round 5 showed intra-kernel
//        flag/arrive protocols cost ~20us; boundaries cost ~2us).
//   k2 : one wave per positive cell — obj correction (t=0 -> t=1), class
//        loss spread over 80 lanes, box GIoU+L1 on lane 0; last-done block
//        reduces dpart+ppart and writes the scalar loss.
// ---------------------------------------------------------------------------

#define IMGF 640.0f
#define NCLS 80
#define NAK 3
#define NB 16
#define NT 32
#define H0 80
#define H1 40
#define H2 20
#define NCELL0 (NB * NAK * H0 * H0) /* 307200 */
#define NCELL1 (NB * NAK * H1 * H1) /*  76800 */
#define NCELL2 (NB * NAK * H2 * H2) /*  19200 */
#define NCELL_TOTAL (NCELL0 + NCELL1 + NCELL2) /* 403200 */
#define MAXPOS 1536 /* <=3 unique cells per target x 512 targets */
#define NDENSE (NCELL_TOTAL / 4) /* 100800 float4 groups */
#define NBLK_D 384               /* dense blocks in k1 */
#define POS_BLOCKS 384           /* k2 blocks: 4 waves each = 1536 waves */
#define HSIZE 4096

__device__ __constant__ float c_anchors[9][2] = {
    {0.0156f, 0.0203f}, {0.025f, 0.0469f}, {0.0516f, 0.0359f},
    {0.0469f, 0.0953f}, {0.0969f, 0.0703f}, {0.0922f, 0.1859f},
    {0.1813f, 0.1406f}, {0.2438f, 0.3094f}, {0.5828f, 0.5094f}};

__device__ inline float sgm(float x) { return 1.f / (1.f + expf(-x)); }
__device__ inline float bcef(float x, float t) {
    return fmaxf(x, 0.f) - x * t + log1pf(expf(-fabsf(x)));
}
__device__ inline float focal_bce(float x, float t) {
    float p = sgm(x);
    float pt = p * t + (1.f - p) * (1.f - t);
    float at = 0.25f * t + 0.75f * (1.f - t);
    float omp = 1.f - pt;
    return at * omp * omp * bcef(x, t);
}

template <int HWC>
__device__ inline float obj4(const float* __restrict__ p, int cis, float inv) {
    int q = cis / HWC; // (b*3+a); compile-time divisor -> magic mul
    int off = cis - q * HWC;
    const float4 v =
        *reinterpret_cast<const float4*>(p + ((size_t)q * 85 + 4) * HWC + off);
    return (focal_bce(v.x, 0.f) + focal_bce(v.y, 0.f) + focal_bce(v.z, 0.f) +
            focal_bce(v.w, 0.f)) *
           inv;
}

// ---------------- k1: dense obj stream + dedicated assign block ----------------
__global__ __launch_bounds__(256) void k1_dense_assign(
    const float* __restrict__ p0, const float* __restrict__ p1,
    const float* __restrict__ p2, const float* __restrict__ boxes,
    const int* __restrict__ labels, int4* __restrict__ list,
    int* __restrict__ countg, int* __restrict__ done,
    float* __restrict__ dpart) {
    if (blockIdx.x == NBLK_D) {
        // ---- assign: LDS hash dedup over 512 targets ----
        __shared__ int hkey[HSIZE];
        __shared__ int hord[HSIZE];
        __shared__ unsigned htm[HSIZE];
        __shared__ int lcount;
        for (int i = threadIdx.x; i < HSIZE; i += 256) {
            hkey[i] = -1;
            hord[i] = -1;
            htm[i] = 0u;
        }
        if (threadIdx.x == 0) lcount = 0;
        __syncthreads();
        for (int half = 0; half < 2; half++) {
            int t = threadIdx.x + (half << 8);
            int b = t >> 5;
            int n = t & 31;
            int lab = labels[t];
            if (lab >= 0 && lab < NCLS) {
                float x1 = boxes[4 * t + 0], y1 = boxes[4 * t + 1];
                float x2 = boxes[4 * t + 2], y2 = boxes[4 * t + 3];
                float bw = fminf(fmaxf((x2 - x1) / IMGF, 1e-6f), 1.0f);
                float bh = fminf(fmaxf((y2 - y1) / IMGF, 1e-6f), 1.0f);
                float area = bw * bh;
                float best = -1.0f;
                int bestk = 0;
#pragma unroll
                for (int k = 0; k < 9; k++) { // strict > == argmax first-max
                    float aw = c_anchors[k][0], ah = c_anchors[k][1];
                    float inter = fminf(bw, aw) * fminf(bh, ah);
                    float iou = inter / (area + aw * ah - inter + 1e-9f);
                    if (iou > best) { best = iou; bestk = k; }
                }
                int s = bestk / 3, a = bestk - 3 * s;
                float cx =
                    fminf(fmaxf((x1 + x2) * 0.5f / IMGF, 0.f), 1.f - 1e-6f);
                float cy =
                    fminf(fmaxf((y1 + y2) * 0.5f / IMGF, 0.f), 1.f - 1e-6f);
                int hw = (s == 0) ? H0 : ((s == 1) ? H1 : H2);
                int basecell =
                    (s == 0) ? 0 : ((s == 1) ? NCELL0 : (NCELL0 + NCELL1));
                float gx = cx * (float)hw, gy = cy * (float)hw;
                int gi = min(max((int)floorf(gx), 0), hw - 1);
                int gj = min(max((int)floorf(gy), 0), hw - 1);
                float fx = gx - (float)gi, fy = gy - (float)gj;
                const int dis[5] = {0, -1, 1, 0, 0};
                const int djs[5] = {0, 0, 0, -1, 1};
                bool keep[5];
                keep[0] = true;
                keep[1] = (fx < 0.5f);
                keep[2] = (fx >= 0.5f);
                keep[3] = (fy < 0.5f);
                keep[4] = (fy >= 0.5f);
#pragma unroll
                for (int c = 0; c < 5; c++) {
                    if (!keep[c]) continue;
                    int ngi = gi + dis[c], ngj = gj + djs[c];
                    if (ngi < 0 || ngi >= hw || ngj < 0 || ngj >= hw) continue;
                    int cell = basecell + ((b * NAK + a) * hw + ngj) * hw + ngi;
                    unsigned h = ((unsigned)cell * 2654435761u) >> 20;
                    while (true) {
                        int old = atomicCAS(&hkey[h], -1, cell);
                        if (old == -1 || old == cell) break;
                        h = (h + 1) & (HSIZE - 1);
                    }
                    // scan-order key: last-writer-wins (XLA scatter-set)
                    atomicMax(&hord[h], c * (NB * NT) + t);
                    atomicOr(&htm[h], 1u << n);
                }
            }
        }
        __syncthreads();
        for (int i = threadIdx.x; i < HSIZE; i += 256) {
            if (hkey[i] >= 0) {
                int p = atomicAdd(&lcount, 1);
                list[p] = make_int4(hkey[i], hord[i], (int)htm[i], 0);
            }
        }
        __syncthreads();
        if (threadIdx.x == 0) {
            *countg = lcount;
            *done = 0; // reset k2's finalize protocol
        }
        return;
    }
    // ---- dense obj: t = 0 baseline, pure coalesced stream ----
    float obj = 0.f;
    for (int i = blockIdx.x * 256 + threadIdx.x; i < NDENSE;
         i += NBLK_D * 256) {
        int c4 = i * 4;
        if (c4 < NCELL0)
            obj += obj4<H0 * H0>(p0, c4, 1.f / (float)NCELL0);
        else if (c4 < NCELL0 + NCELL1)
            obj += obj4<H1 * H1>(p1, c4 - NCELL0, 1.f / (float)NCELL1);
        else
            obj += obj4<H2 * H2>(p2, c4 - NCELL0 - NCELL1, 1.f / (float)NCELL2);
    }
#pragma unroll
    for (int off = 32; off > 0; off >>= 1) obj += __shfl_down(obj, off, 64);
    __shared__ float redd[4];
    if ((threadIdx.x & 63) == 0) redd[threadIdx.x >> 6] = obj;
    __syncthreads();
    if (threadIdx.x == 0)
        dpart[blockIdx.x] = redd[0] + redd[1] + redd[2] + redd[3];
}

// ---------------- k2: positives (one wave/cell) + fused finalize ----------------
__global__ __launch_bounds__(256) void k2_pos_finalize(
    const float* __restrict__ p0, const float* __restrict__ p1,
    const float* __restrict__ p2, const float* __restrict__ boxes,
    const int* __restrict__ labels, const int4* __restrict__ list,
    const int* __restrict__ countg, int* __restrict__ done,
    const float* __restrict__ dpart, float* __restrict__ ppart,
    float* __restrict__ out) {
    int cnt = *countg;
    int w = blockIdx.x * 4 + (threadIdx.x >> 6);
    int lane = threadIdx.x & 63;
    if (w < cnt) {
        int4 rec = list[w];
        int idx = rec.x;
        unsigned tm = (unsigned)rec.z;
        const float* p;
        int hw, s, base;
        float inv;
        if (idx < NCELL0) {
            p = p0; hw = H0; s = 0; base = 0; inv = 1.f / (float)NCELL0;
        } else if (idx < NCELL0 + NCELL1) {
            p = p1; hw = H1; s = 1; base = NCELL0; inv = 1.f / (float)NCELL1;
        } else {
            p = p2; hw = H2; s = 2; base = NCELL0 + NCELL1;
            inv = 1.f / (float)NCELL2;
        }
        int cell = idx - base;
        int x = cell % hw;
        int r = cell / hw;
        int y = r % hw;
        r /= hw;
        int a = r % NAK;
        int b = r / NAK;
        size_t HW = (size_t)hw * hw;
        const float* pc =
            p + (size_t)(b * 255 + a * 85) * HW + (size_t)y * hw + x;
        // class loss: 80 classes spread over lanes (2 parallel rounds)
        float cl = 0.f;
#pragma unroll
        for (int rep = 0; rep < 2; rep++) {
            int c = lane + 64 * rep;
            if (c < NCLS) {
                float tt = 0.f;
                unsigned tmp = tm;
                while (tmp) {
                    int n = __ffs(tmp) - 1;
                    tmp &= tmp - 1;
                    if (labels[(b << 5) + n] == c) tt = 1.f;
                }
                cl += bcef(pc[(size_t)(5 + c) * HW], tt);
            }
        }
#pragma unroll
        for (int off = 32; off > 0; off >>= 1) cl += __shfl_down(cl, off, 64);
        if (lane == 0) {
            // obj correction t=0 -> t=1 (k1 assumed t=0 everywhere)
            float pobj = pc[4 * HW];
            float objc = (focal_bce(pobj, 1.f) - focal_bce(pobj, 0.f)) * inv;
            // box loss: decode last scatter writer
            int wn = rec.y & (NB * NT - 1); // order % 512
            float bx1 = boxes[4 * wn + 0], by1 = boxes[4 * wn + 1];
            float bx2 = boxes[4 * wn + 2], by2 = boxes[4 * wn + 3];
            float tw = fminf(fmaxf((bx2 - bx1) / IMGF, 1e-6f), 1.f);
            float th = fminf(fmaxf((by2 - by1) / IMGF, 1e-6f), 1.f);
            float tcx =
                fminf(fmaxf((bx1 + bx2) * 0.5f / IMGF, 0.f), 1.f - 1e-6f);
            float tcy =
                fminf(fmaxf((by1 + by2) * 0.5f / IMGF, 0.f), 1.f - 1e-6f);
            float l0 = pc[0], l1 = pc[HW], l2 = pc[2 * HW], l3 = pc[3 * HW];
            float pcx = ((float)x + 2.f * sgm(l0) - 0.5f) / (float)hw;
            float pcy = ((float)y + 2.f * sgm(l1) - 0.5f) / (float)hw;
            float sw = 2.f * sgm(l2), sh = 2.f * sgm(l3);
            float pw = sw * sw * c_anchors[s * 3 + a][0];
            float ph = sh * sh * c_anchors[s * 3 + a][1];
            float px1 = pcx - pw * 0.5f, px2 = pcx + pw * 0.5f;
            float py1 = pcy - ph * 0.5f, py2 = pcy + ph * 0.5f;
            float tx1 = tcx - tw * 0.5f, tx2 = tcx + tw * 0.5f;
            float ty1 = tcy - th * 0.5f, ty2 = tcy + th * 0.5f;
            float iw = fmaxf(fminf(px2, tx2) - fmaxf(px1, tx1), 0.f);
            float ih = fmaxf(fminf(py2, ty2) - fmaxf(py1, ty1), 0.f);
            float it = iw * ih;
            float un = pw * ph + tw * th - it + 1e-9f;
            float iou = it / un;
            float enc = (fmaxf(px2, tx2) - fminf(px1, tx1)) *
                            (fmaxf(py2, ty2) - fminf(py1, ty1)) +
                        1e-9f;
            float giou = iou - (enc - un) / enc;
            float l1l = fabsf(pcx - tcx) + fabsf(pcy - tcy) + fabsf(pw - tw) +
                        fabsf(ph - th);
            ppart[3 * w] = cl;
            ppart[3 * w + 1] = 1.f - giou + l1l;
            ppart[3 * w + 2] = objc;
        }
    }
    // ---- fused finalize: last block to finish reduces everything ----
    __shared__ int amLast;
    __syncthreads();
    if (threadIdx.x == 0) {
        __threadfence(); // release our partial writes
        amLast = (atomicAdd(done, 1) == POS_BLOCKS - 1) ? 1 : 0;
    }
    __syncthreads();
    if (amLast) {
        __threadfence(); // acquire other blocks' writes
        float o = 0.f, cls = 0.f, box = 0.f;
        for (int i = threadIdx.x; i < NBLK_D; i += 256) o += dpart[i];
        for (int i = threadIdx.x; i < cnt; i += 256) {
            cls += ppart[3 * i];
            box += ppart[3 * i + 1];
            o += ppart[3 * i + 2];
        }
#pragma unroll
        for (int off = 32; off > 0; off >>= 1) {
            o += __shfl_down(o, off, 64);
            cls += __shfl_down(cls, off, 64);
            box += __shfl_down(box, off, 64);
        }
        __shared__ float redf[4][3];
        int wv = threadIdx.x >> 6;
        if ((threadIdx.x & 63) == 0) {
            redf[wv][0] = o;
            redf[wv][1] = cls;
            redf[wv][2] = box;
        }
        __syncthreads();
        if (threadIdx.x == 0) {
            float oo = redf[0][0] + redf[1][0] + redf[2][0] + redf[3][0];
            float cc = redf[0][1] + redf[1][1] + redf[2][1] + redf[3][1];
            float bb = redf[0][2] + redf[1][2] + redf[2][2] + redf[3][2];
            float d = fmaxf((float)cnt, 1.f);
            out[0] = oo + (cc + 5.f * bb) / d;
        }
    }
}

extern "C" void kernel_launch(void* const* d_in, const int* in_sizes, int n_in,
                              void* d_out, int out_size, void* d_ws,
                              size_t ws_size, hipStream_t stream) {
    const float* p0 = (const float*)d_in[0];
    const float* p1 = (const float*)d_in[1];
    const float* p2 = (const float*)d_in[2];
    const float* boxes = (const float*)d_in[3];
    const int* labels = (const int*)d_in[4];
    float* out = (float*)d_out;

    // ws layout (every region read is written earlier in the same call):
    // [list int4 x MAXPOS][countg][done][pad][dpart f32 x NBLK_D]
    // [ppart f32 x MAXPOS*3]
    char* ws = (char*)d_ws;
    int4* list = (int4*)ws;
    size_t off = (size_t)MAXPOS * 16; // 24576
    int* countg = (int*)(ws + off);
    int* done = (int*)(ws + off + 4);
    off += 16;
    float* dpart = (float*)(ws + off);
    off += (size_t)NBLK_D * 4;
    float* ppart = (float*)(ws + off);

    k1_dense_assign<<<NBLK_D + 1, 256, 0, stream>>>(p0, p1, p2, boxes, labels,
                                                    list, countg, done, dpart);
    k2_pos_finalize<<<POS_BLOCKS, 256, 0, stream>>>(p0, p1, p2, boxes, labels,
                                                    list, countg, done, dpart,
                                                    ppart, out);
}